// Round 15
// baseline (160.202 us; speedup 1.0000x reference)
//
#include <hip/hip_runtime.h>
#include <math.h>

// Problem dims (fixed by the reference)
#define B_ 8
#define L_ 8192
#define H_ 128
#define N_ 32
#define C_ 128   // chunks along L
#define T_ 64    // chunk length

// ws layout:
//   Wh   ushort[256*128]     @ 0        (64 KB)  fp16 out_w [g][h]
//   Kh   ushort[128*64*64]   @ 65536    (1 MB)   fp16 Klo[h][t][j] (Toeplitz)
//   Ph   ushort[128*64*64]   @ 1114112  (1 MB)   fp16 P[h][t][m']  (state inj)
//   Vh   ushort[128*64*64]   @ 2162688  (1 MB)   fp16 V[h][m'][j]  (Vandermonde)
//   gy   ushort[B_*H_*L_]    @ 3211264  (16 MB)  fp16 gy [b][h][l'], l'=t*128+c
//   part float[1024]         @ 19988480 (4 KB)
//   dcnt uint[1]             @ 19992576 (4 B)    k_mix last-block counter

typedef _Float16 half8 __attribute__((ext_vector_type(8)));
typedef __attribute__((ext_vector_type(4))) float f32x4;

__device__ __forceinline__ float gelu_tanh(float y) {
    float t = 0.7978845608028654f * fmaf(0.044715f, y * y * y, y);
    float e = __expf(2.f * t);
    float th = 1.f - __fdividef(2.f, e + 1.f);
    return 0.5f * y * (1.f + th);
}
__device__ __forceinline__ unsigned short f2h(float f) {
    _Float16 h = (_Float16)f;
    return *(unsigned short*)&h;
}
__device__ __forceinline__ float h2f(unsigned short u) {
    return (float)(*(const _Float16*)&u);
}

// ---------------------------------------------------------------------------
// k_prep: block = (which, h), grid 384 — 3x parallel vs R14's 128 blocks.
// All blocks compute wtab/coefs (cheap, redundant); each writes ONE matrix.
// which==2 also converts out_w rows and zeroes the k_mix last-block counter.
// ---------------------------------------------------------------------------
__global__ __launch_bounds__(256) void k_prep(
    const float* __restrict__ log_dt, const float* __restrict__ log_A_real,
    const float* __restrict__ A_imag, const float* __restrict__ C_re,
    const float* __restrict__ C_im, const float* __restrict__ out_w,
    unsigned short* __restrict__ Wh, unsigned short* __restrict__ Kh,
    unsigned short* __restrict__ Ph, unsigned short* __restrict__ Vh,
    unsigned int* __restrict__ dcnt)
{
    const int blk = blockIdx.x;
    const int h = blk & 127;
    const int which = blk >> 7;            // 0:K  1:P  2:V(+Wh,+dcnt)
    const int tid = threadIdx.x;
    __shared__ float2 wtab[65][N_];
    __shared__ float2 coefs[N_];
    __shared__ float Kd[64];

    float dt = expf(log_dt[h]);
#pragma unroll
    for (int it = 0; it < 9; ++it) {
        int idx = it * 256 + tid;
        if (idx < 65 * N_) {
            int d = idx >> 5, n = idx & 31;
            float Ar = -expf(log_A_real[h * N_ + n]);
            float Ai = A_imag[h * N_ + n];
            float ar = dt * Ar * (float)d, ai = dt * Ai * (float)d;
            float er = expf(ar);
            wtab[d][n] = make_float2(er * cosf(ai), er * sinf(ai));
        }
    }
    if (tid < N_) {
        int n = tid;
        float Ar = -expf(log_A_real[h * N_ + n]);
        float Ai = A_imag[h * N_ + n];
        float ar = dt * Ar, ai = dt * Ai;
        float er = expf(ar);
        float wr = er * cosf(ai), wi = er * sinf(ai);
        float inv = 1.f / (Ar * Ar + Ai * Ai);
        float numr = wr - 1.f, numi = wi;
        float qr = (numr * Ar + numi * Ai) * inv;
        float qi = (numi * Ar - numr * Ai) * inv;
        coefs[n] = make_float2(C_re[h * N_ + n] * qr - C_im[h * N_ + n] * qi,
                               C_re[h * N_ + n] * qi + C_im[h * N_ + n] * qr);
    }
    __syncthreads();

    if (which == 0) {
        if (tid < 64) {
            float s = 0.f;
#pragma unroll
            for (int n = 0; n < N_; ++n) {
                float2 cf = coefs[n]; float2 w = wtab[tid][n];
                s += cf.x * w.x - cf.y * w.y;
            }
            Kd[tid] = 2.f * s;
        }
        __syncthreads();
#pragma unroll
        for (int it = 0; it < 16; ++it) {
            int idx = it * 256 + tid;          // t*64 + j
            int t = idx >> 6, j = idx & 63;
            Kh[h * 4096 + idx] = f2h((t >= j) ? Kd[t - j] : 0.f);
        }
    } else if (which == 1) {
#pragma unroll
        for (int it = 0; it < 16; ++it) {
            int idx = it * 256 + tid;          // t*64 + m
            int t = idx >> 6, m = idx & 63, n = m & 31;
            float2 cf = coefs[n]; float2 w = wtab[t + 1][n];
            float re = cf.x * w.x - cf.y * w.y;
            float im = cf.x * w.y + cf.y * w.x;
            Ph[h * 4096 + idx] = f2h((m < 32) ? 2.f * re : -2.f * im);
        }
    } else {
#pragma unroll
        for (int it = 0; it < 16; ++it) {
            int idx = it * 256 + tid;          // m*64 + j
            int m = idx >> 6, j = idx & 63, n = m & 31;
            float2 w = wtab[63 - j][n];
            Vh[h * 4096 + idx] = f2h((m < 32) ? w.x : w.y);
        }
        {   // out_w rows g = 2h, 2h+1 -> fp16
            int g = 2 * h + (tid >> 7), j = tid & 127;
            Wh[g * 128 + j] = f2h(out_w[g * 128 + j]);
        }
        if (h == 0 && tid == 0) *dcnt = 0u;    // k_prep completes before k_mix
    }
}

// ---------------------------------------------------------------------------
// k_s4d: MFMA-Toeplitz S4D (UNCHANGED from R14).
// ---------------------------------------------------------------------------
__global__ __launch_bounds__(256) void k_s4d(
    const float* __restrict__ x, const float* __restrict__ enc_w,
    const float* __restrict__ enc_b, const float* __restrict__ log_dt,
    const float* __restrict__ log_A_real, const float* __restrict__ A_imag,
    const float* __restrict__ Dp, const unsigned short* __restrict__ Kh,
    const unsigned short* __restrict__ Ph, const unsigned short* __restrict__ Vh,
    unsigned short* __restrict__ gy)
{
    const int bh = blockIdx.x;
    const int b = bh >> 7, h = bh & (H_ - 1);
    const int tid = threadIdx.x;
    const int lane = tid & 63, wq = tid >> 6;
    const int mrow = lane & 15, quad = lane >> 4;

    __shared__ unsigned short Ut[C_][72];          // [c][j] fp16 u (18.4 KB)
    __shared__ __align__(16) char scratch[18432];  // E16 / Sx / St (18.4 KB)
    __shared__ float2 wTpow[7][N_];                // 1.8 KB
    unsigned short* E16 = (unsigned short*)scratch;   // [m(64)][c] stride 136
    float2*         Sx  = (float2*)scratch;           // [n(32)][c(64)]
    unsigned short* St  = (unsigned short*)scratch;   // [c(128)][m'] stride 72

    if (tid < N_) {
        int idx = h * N_ + tid;
        float dt = expf(log_dt[h]);
        float Ar = -expf(log_A_real[idx]);
        float Ai = A_imag[idx];
        float ar = dt * Ar * (float)T_, ai = dt * Ai * (float)T_;
        float er = expf(ar);
        float pr = er * cosf(ai), pi = er * sinf(ai);
#pragma unroll
        for (int k = 0; k < 7; ++k) {
            wTpow[k][tid] = make_float2(pr, pi);
            float nr = pr * pr - pi * pi;
            pi = 2.f * pr * pi; pr = nr;
        }
    }

    // ---- stage: u = enc(x) -> Ut[c][j] fp16 ----
    const float ew0 = enc_w[h], ew1 = enc_w[H_ + h], eb = enc_b[h];
    {
        int c = tid >> 1, j0 = (tid & 1) * 32;
        const float4* xp = (const float4*)((const float2*)x + (size_t)b * L_
                                           + c * 64 + j0);
#pragma unroll
        for (int i = 0; i < 16; ++i) {
            float4 xv = xp[i];
            float u0 = fmaf(xv.x, ew0, fmaf(xv.y, ew1, eb));
            float u1 = fmaf(xv.z, ew0, fmaf(xv.w, ew1, eb));
            unsigned int pk = (unsigned)f2h(u0) | ((unsigned)f2h(u1) << 16);
            *(unsigned int*)&Ut[c][j0 + 2 * i] = pk;
        }
    }
    __syncthreads();

    // ---- GEMM E[m 64][c 128] = V[m][j] @ U[j][c] -> fp16 E16 ----
    {
        f32x4 acc[8];
#pragma unroll
        for (int nt = 0; nt < 8; ++nt) acc[nt] = (f32x4){0.f, 0.f, 0.f, 0.f};
        const unsigned short* Arow = Vh + h * 4096 + (wq * 16 + mrow) * 64;
#pragma unroll
        for (int ks = 0; ks < 2; ++ks) {
            int k0 = ks * 32 + quad * 8;
            half8 af = *(const half8*)(Arow + k0);
#pragma unroll
            for (int nt = 0; nt < 8; ++nt) {
                half8 bf = *(const half8*)&Ut[nt * 16 + mrow][k0];
                acc[nt] = __builtin_amdgcn_mfma_f32_16x16x32_f16(
                    af, bf, acc[nt], 0, 0, 0);
            }
        }
#pragma unroll
        for (int nt = 0; nt < 8; ++nt) {
            int cc = nt * 16 + mrow;
#pragma unroll
            for (int r = 0; r < 4; ++r)
                E16[(wq * 16 + quad * 4 + r) * 136 + cc] = f2h(acc[nt][r]);
        }
    }
    __syncthreads();

    // ---- scan: 4 waves, wave = (cHalf, nHalf), 16 n per thread ----
    float zr[16], zi[16];
    const int cHalf = wq & 1, nHalf = wq >> 1;
    const int n0 = nHalf * 16;
    const int c = cHalf * 64 + lane;
#pragma unroll
    for (int j = 0; j < 16; ++j) {
        zr[j] = h2f(E16[(n0 + j) * 136 + c]);
        zi[j] = h2f(E16[(32 + n0 + j) * 136 + c]);
    }
    __syncthreads();            // all E16 reads done before Sx overwrites
#pragma unroll
    for (int k = 0; k < 6; ++k) {
        int s = 1 << k;
        float mask = (lane >= s) ? 1.f : 0.f;
#pragma unroll
        for (int j = 0; j < 16; ++j) {
            float2 q = wTpow[k][n0 + j];
            float vr = __shfl_up(zr[j], s, 64);
            float vi = __shfl_up(zi[j], s, 64);
            float adr = fmaf(q.x, vr, -(q.y * vi));
            float adi = fmaf(q.x, vi, q.y * vr);
            zr[j] = fmaf(mask, adr, zr[j]);
            zi[j] = fmaf(mask, adi, zi[j]);
        }
    }
    if (cHalf == 0) {           // publish inclusive scans of low c-half
#pragma unroll
        for (int j = 0; j < 16; ++j)
            Sx[(n0 + j) * 64 + lane] = make_float2(zr[j], zi[j]);
    }
    __syncthreads();
    if (cHalf == 1) {           // s=64 combine with uniform weight wT^64
#pragma unroll
        for (int j = 0; j < 16; ++j) {
            float2 q = wTpow[6][n0 + j];
            float2 v = Sx[(n0 + j) * 64 + lane];
            zr[j] = fmaf(q.x, v.x, fmaf(-q.y, v.y, zr[j]));
            zi[j] = fmaf(q.x, v.y, fmaf(q.y, v.x, zi[j]));
        }
    }
    {                           // shift by one chunk: S_in[c] = I[c-1]
        bool l0 = (lane == 0);
#pragma unroll
        for (int j = 0; j < 16; ++j) {
            float2 bv = Sx[(n0 + j) * 64 + 63];
            float br = (cHalf == 1) ? bv.x : 0.f;
            float bi = (cHalf == 1) ? bv.y : 0.f;
            float tr = __shfl_up(zr[j], 1, 64);
            float ti = __shfl_up(zi[j], 1, 64);
            zr[j] = l0 ? br : tr;
            zi[j] = l0 ? bi : ti;
        }
    }
    __syncthreads();            // all Sx reads done before St overwrites
    {
#pragma unroll
        for (int j2 = 0; j2 < 8; ++j2) {
            unsigned int p0 = (unsigned)f2h(zr[2 * j2]) |
                              ((unsigned)f2h(zr[2 * j2 + 1]) << 16);
            unsigned int p1 = (unsigned)f2h(zi[2 * j2]) |
                              ((unsigned)f2h(zi[2 * j2 + 1]) << 16);
            *(unsigned int*)&St[c * 72 + n0 + 2 * j2] = p0;
            *(unsigned int*)&St[c * 72 + 32 + n0 + 2 * j2] = p1;
        }
    }
    __syncthreads();

    // ---- GEMM Y[t][c] = Klo@U + P@S; epilogue u from Ut; fp16 gy store ----
    {
        f32x4 acc[8];
#pragma unroll
        for (int nt = 0; nt < 8; ++nt) acc[nt] = (f32x4){0.f, 0.f, 0.f, 0.f};
        const unsigned short* Krow = Kh + h * 4096 + (wq * 16 + mrow) * 64;
#pragma unroll
        for (int ks = 0; ks < 2; ++ks) {
            int k0 = ks * 32 + quad * 8;
            half8 af = *(const half8*)(Krow + k0);
#pragma unroll
            for (int nt = 0; nt < 8; ++nt) {
                half8 bf = *(const half8*)&Ut[nt * 16 + mrow][k0];
                acc[nt] = __builtin_amdgcn_mfma_f32_16x16x32_f16(
                    af, bf, acc[nt], 0, 0, 0);
            }
        }
        const unsigned short* Prow = Ph + h * 4096 + (wq * 16 + mrow) * 64;
#pragma unroll
        for (int ks = 0; ks < 2; ++ks) {
            int k0 = ks * 32 + quad * 8;
            half8 af = *(const half8*)(Prow + k0);
#pragma unroll
            for (int nt = 0; nt < 8; ++nt) {
                half8 bf = *(const half8*)&St[(nt * 16 + mrow) * 72 + k0];
                acc[nt] = __builtin_amdgcn_mfma_f32_16x16x32_f16(
                    af, bf, acc[nt], 0, 0, 0);
            }
        }
        const float Dh = Dp[h];
        unsigned short* gyb = gy + (size_t)bh * L_;
#pragma unroll
        for (int nt = 0; nt < 8; ++nt) {
            int cc = nt * 16 + mrow;
#pragma unroll
            for (int r = 0; r < 4; ++r) {
                int t = wq * 16 + quad * 4 + r;
                float u = h2f(Ut[cc][t]);
                float y = fmaf(Dh, u, acc[nt][r]);
                gyb[t * 128 + cc] = f2h(gelu_tanh(y));
            }
        }
    }
}

// ---------------------------------------------------------------------------
// k_mix: fp16 MFMA GLU mix + pooled decode. MFMA body unchanged from R14;
// k_final is now fused via the last-block pattern (dcnt zeroed by k_prep).
// ---------------------------------------------------------------------------
#define BPAD 136
__global__ __launch_bounds__(256) void k_mix(
    const unsigned short* __restrict__ Wh, const unsigned short* __restrict__ gy,
    const float* __restrict__ out_b, const float* __restrict__ dec_w,
    const float* __restrict__ dec_b, float* __restrict__ part,
    unsigned int* __restrict__ dcnt, float* __restrict__ out)
{
    __shared__ unsigned short Bt[64 * BPAD];   // [v][h] fp16 tile (17.4 KB)
    __shared__ float red[4];
    __shared__ unsigned int isLast;

    const int blk = blockIdx.x;                // = b*128 + t*2 + ch
    const int b = blk >> 7;
    const int t = (blk >> 1) & 63, ch = blk & 1;
    const int tid = threadIdx.x;
    const int wq = tid >> 6, lane = tid & 63;

    // ---- stage: 128h x 64v fp16 transpose (uint4 = 8 ushorts per load) ----
    const unsigned short* gsrc = gy + (size_t)(b * H_) * L_ + t * 128 + ch * 64;
#pragma unroll
    for (int it = 0; it < 4; ++it) {
        int idx = it * 256 + tid;
        int h = idx >> 3, v0 = (idx & 7) * 8;
        uint4 q = *(const uint4*)(gsrc + (size_t)h * L_ + v0);
        Bt[(v0 + 0) * BPAD + h] = (unsigned short)(q.x & 0xFFFF);
        Bt[(v0 + 1) * BPAD + h] = (unsigned short)(q.x >> 16);
        Bt[(v0 + 2) * BPAD + h] = (unsigned short)(q.y & 0xFFFF);
        Bt[(v0 + 3) * BPAD + h] = (unsigned short)(q.y >> 16);
        Bt[(v0 + 4) * BPAD + h] = (unsigned short)(q.z & 0xFFFF);
        Bt[(v0 + 5) * BPAD + h] = (unsigned short)(q.z >> 16);
        Bt[(v0 + 6) * BPAD + h] = (unsigned short)(q.w & 0xFFFF);
        Bt[(v0 + 7) * BPAD + h] = (unsigned short)(q.w >> 16);
    }
    __syncthreads();

    const int ga = wq * 32;
    const int gg = 128 + wq * 32;
    const int mrow = lane & 15;
    const int quad = lane >> 4;
    f32x4 accA[2][4], accG[2][4];
#pragma unroll
    for (int mt = 0; mt < 2; ++mt)
#pragma unroll
        for (int nt = 0; nt < 4; ++nt) {
            accA[mt][nt] = (f32x4){0.f, 0.f, 0.f, 0.f};
            accG[mt][nt] = (f32x4){0.f, 0.f, 0.f, 0.f};
        }

#pragma unroll
    for (int k = 0; k < 4; ++k) {
        const int h0 = k * 32 + quad * 8;
        half8 bfr[4];
#pragma unroll
        for (int nt = 0; nt < 4; ++nt) {
            int v = nt * 16 + mrow;
            bfr[nt] = *(const half8*)(Bt + v * BPAD + h0);
        }
#pragma unroll
        for (int mt = 0; mt < 2; ++mt) {
            half8 ah = *(const half8*)(Wh + (ga + mt * 16 + mrow) * 128 + h0);
            half8 ag = *(const half8*)(Wh + (gg + mt * 16 + mrow) * 128 + h0);
#pragma unroll
            for (int nt = 0; nt < 4; ++nt) {
                accA[mt][nt] = __builtin_amdgcn_mfma_f32_16x16x32_f16(
                    ah, bfr[nt], accA[mt][nt], 0, 0, 0);
                accG[mt][nt] = __builtin_amdgcn_mfma_f32_16x16x32_f16(
                    ag, bfr[nt], accG[mt][nt], 0, 0, 0);
            }
        }
    }

    float s = 0.f;
#pragma unroll
    for (int mt = 0; mt < 2; ++mt) {
        float4 obA = *(const float4*)(out_b + ga + mt * 16 + quad * 4);
        float4 obG = *(const float4*)(out_b + gg + mt * 16 + quad * 4);
        float4 dv  = *(const float4*)(dec_w + ga + mt * 16 + quad * 4);
#pragma unroll
        for (int nt = 0; nt < 4; ++nt) {
#pragma unroll
            for (int r = 0; r < 4; ++r) {
                float a  = accA[mt][nt][r] + ((const float*)&obA)[r];
                float zg = accG[mt][nt][r] + ((const float*)&obG)[r];
                float sig = __fdividef(1.f, 1.f + __expf(-zg));
                s = fmaf(((const float*)&dv)[r], a * sig, s);
            }
        }
    }
#pragma unroll
    for (int off = 32; off; off >>= 1) s += __shfl_down(s, off, 64);
    if (lane == 0) red[wq] = s;
    __syncthreads();

    if (tid == 0) {
        part[blk] = red[0] + red[1] + red[2] + red[3];
        __threadfence();                       // device-scope: publish part
        unsigned int old = atomicAdd(dcnt, 1u);
        isLast = (old == (unsigned)(B_ * 128 - 1)) ? 1u : 0u;
    }
    __syncthreads();

    if (isLast) {                              // 1024th block: final reduce
        const volatile float* pv = part;       // sc0 loads, bypass stale L1
        int bb = tid >> 5, i = tid & 31;
        float v = pv[bb * 128 + i] + pv[bb * 128 + 32 + i]
                + pv[bb * 128 + 64 + i] + pv[bb * 128 + 96 + i];
#pragma unroll
        for (int off = 16; off; off >>= 1) v += __shfl_down(v, off, 32);
        if (i == 0) out[bb] = fmaf(v, 1.0f / (float)L_, dec_b[0]);
    }
}

// ---------------------------------------------------------------------------
extern "C" void kernel_launch(void* const* d_in, const int* in_sizes, int n_in,
                              void* d_out, int out_size, void* d_ws, size_t ws_size,
                              hipStream_t stream)
{
    const float* x         = (const float*)d_in[0];
    const float* enc_w     = (const float*)d_in[1];
    const float* enc_b     = (const float*)d_in[2];
    const float* log_dt    = (const float*)d_in[3];
    const float* log_A_real= (const float*)d_in[4];
    const float* A_imag    = (const float*)d_in[5];
    const float* C_re      = (const float*)d_in[6];
    const float* C_im      = (const float*)d_in[7];
    const float* Dp        = (const float*)d_in[8];
    const float* out_w     = (const float*)d_in[9];
    const float* out_b     = (const float*)d_in[10];
    const float* dec_w     = (const float*)d_in[11];
    const float* dec_b     = (const float*)d_in[12];
    float* out = (float*)d_out;

    char* ws = (char*)d_ws;
    unsigned short* Wh = (unsigned short*)(ws);
    unsigned short* Kh = (unsigned short*)(ws + 65536);
    unsigned short* Ph = (unsigned short*)(ws + 1114112);
    unsigned short* Vh = (unsigned short*)(ws + 2162688);
    unsigned short* gy = (unsigned short*)(ws + 3211264);
    float* part        = (float*)(ws + 19988480);
    unsigned int* dcnt = (unsigned int*)(ws + 19992576);

    k_prep<<<3 * H_, 256, 0, stream>>>(log_dt, log_A_real, A_imag, C_re, C_im,
                                       out_w, Wh, Kh, Ph, Vh, dcnt);
    k_s4d<<<B_ * H_, 256, 0, stream>>>(x, enc_w, enc_b, log_dt, log_A_real,
                                       A_imag, Dp, Kh, Ph, Vh, gy);
    k_mix<<<B_ * 128, 256, 0, stream>>>(Wh, gy, out_b, dec_w, dec_b, part,
                                        dcnt, out);
}

// Round 16
// 140.771 us; speedup vs baseline: 1.1380x; 1.1380x over previous
//
#include <hip/hip_runtime.h>
#include <math.h>

// Problem dims (fixed by the reference)
#define B_ 8
#define L_ 8192
#define H_ 128
#define N_ 32
#define C_ 128   // chunks along L
#define T_ 64    // chunk length

// ws layout:
//   Wh   ushort[256*128]     @ 0        (64 KB)  fp16 out_w [g][h]
//   Kh   ushort[128*64*64]   @ 65536    (1 MB)   fp16 Klo[h][t][j] (Toeplitz)
//   Ph   ushort[128*64*64]   @ 1114112  (1 MB)   fp16 P[h][t][m']  (state inj)
//   Vh   ushort[128*64*64]   @ 2162688  (1 MB)   fp16 V[h][m'][j]  (Vandermonde)
//   gy   ushort[B_*H_*L_]    @ 3211264  (16 MB)  fp16 gy [b][h][l'], l'=t*128+c
//   part float[1024]         @ 19988480 (4 KB)

typedef _Float16 half8 __attribute__((ext_vector_type(8)));
typedef __attribute__((ext_vector_type(4))) float f32x4;

__device__ __forceinline__ float gelu_tanh(float y) {
    float t = 0.7978845608028654f * fmaf(0.044715f, y * y * y, y);
    float e = __expf(2.f * t);
    float th = 1.f - __fdividef(2.f, e + 1.f);
    return 0.5f * y * (1.f + th);
}
__device__ __forceinline__ unsigned short f2h(float f) {
    _Float16 h = (_Float16)f;
    return *(unsigned short*)&h;
}
__device__ __forceinline__ float h2f(unsigned short u) {
    return (float)(*(const _Float16*)&u);
}

// ---------------------------------------------------------------------------
// k_prep: block = (which, h), grid 384. All blocks compute wtab/coefs
// (cheap, redundant); each writes ONE matrix. No dcnt (R15's fused-final
// fence pattern cost ~20us — reverted).
// ---------------------------------------------------------------------------
__global__ __launch_bounds__(256) void k_prep(
    const float* __restrict__ log_dt, const float* __restrict__ log_A_real,
    const float* __restrict__ A_imag, const float* __restrict__ C_re,
    const float* __restrict__ C_im, const float* __restrict__ out_w,
    unsigned short* __restrict__ Wh, unsigned short* __restrict__ Kh,
    unsigned short* __restrict__ Ph, unsigned short* __restrict__ Vh)
{
    const int blk = blockIdx.x;
    const int h = blk & 127;
    const int which = blk >> 7;            // 0:K  1:P  2:V(+Wh)
    const int tid = threadIdx.x;
    __shared__ float2 wtab[65][N_];
    __shared__ float2 coefs[N_];
    __shared__ float Kd[64];

    float dt = expf(log_dt[h]);
#pragma unroll
    for (int it = 0; it < 9; ++it) {
        int idx = it * 256 + tid;
        if (idx < 65 * N_) {
            int d = idx >> 5, n = idx & 31;
            float Ar = -expf(log_A_real[h * N_ + n]);
            float Ai = A_imag[h * N_ + n];
            float ar = dt * Ar * (float)d, ai = dt * Ai * (float)d;
            float er = expf(ar);
            wtab[d][n] = make_float2(er * cosf(ai), er * sinf(ai));
        }
    }
    if (tid < N_) {
        int n = tid;
        float Ar = -expf(log_A_real[h * N_ + n]);
        float Ai = A_imag[h * N_ + n];
        float ar = dt * Ar, ai = dt * Ai;
        float er = expf(ar);
        float wr = er * cosf(ai), wi = er * sinf(ai);
        float inv = 1.f / (Ar * Ar + Ai * Ai);
        float numr = wr - 1.f, numi = wi;
        float qr = (numr * Ar + numi * Ai) * inv;
        float qi = (numi * Ar - numr * Ai) * inv;
        coefs[n] = make_float2(C_re[h * N_ + n] * qr - C_im[h * N_ + n] * qi,
                               C_re[h * N_ + n] * qi + C_im[h * N_ + n] * qr);
    }
    __syncthreads();

    if (which == 0) {
        if (tid < 64) {
            float s = 0.f;
#pragma unroll
            for (int n = 0; n < N_; ++n) {
                float2 cf = coefs[n]; float2 w = wtab[tid][n];
                s += cf.x * w.x - cf.y * w.y;
            }
            Kd[tid] = 2.f * s;
        }
        __syncthreads();
#pragma unroll
        for (int it = 0; it < 16; ++it) {
            int idx = it * 256 + tid;          // t*64 + j
            int t = idx >> 6, j = idx & 63;
            Kh[h * 4096 + idx] = f2h((t >= j) ? Kd[t - j] : 0.f);
        }
    } else if (which == 1) {
#pragma unroll
        for (int it = 0; it < 16; ++it) {
            int idx = it * 256 + tid;          // t*64 + m
            int t = idx >> 6, m = idx & 63, n = m & 31;
            float2 cf = coefs[n]; float2 w = wtab[t + 1][n];
            float re = cf.x * w.x - cf.y * w.y;
            float im = cf.x * w.y + cf.y * w.x;
            Ph[h * 4096 + idx] = f2h((m < 32) ? 2.f * re : -2.f * im);
        }
    } else {
#pragma unroll
        for (int it = 0; it < 16; ++it) {
            int idx = it * 256 + tid;          // m*64 + j
            int m = idx >> 6, j = idx & 63, n = m & 31;
            float2 w = wtab[63 - j][n];
            Vh[h * 4096 + idx] = f2h((m < 32) ? w.x : w.y);
        }
        {   // out_w rows g = 2h, 2h+1 -> fp16
            int g = 2 * h + (tid >> 7), j = tid & 127;
            Wh[g * 128 + j] = f2h(out_w[g * 128 + j]);
        }
    }
}

// ---------------------------------------------------------------------------
// k_s4d: MFMA-Toeplitz S4D (UNCHANGED from R14).
// ---------------------------------------------------------------------------
__global__ __launch_bounds__(256) void k_s4d(
    const float* __restrict__ x, const float* __restrict__ enc_w,
    const float* __restrict__ enc_b, const float* __restrict__ log_dt,
    const float* __restrict__ log_A_real, const float* __restrict__ A_imag,
    const float* __restrict__ Dp, const unsigned short* __restrict__ Kh,
    const unsigned short* __restrict__ Ph, const unsigned short* __restrict__ Vh,
    unsigned short* __restrict__ gy)
{
    const int bh = blockIdx.x;
    const int b = bh >> 7, h = bh & (H_ - 1);
    const int tid = threadIdx.x;
    const int lane = tid & 63, wq = tid >> 6;
    const int mrow = lane & 15, quad = lane >> 4;

    __shared__ unsigned short Ut[C_][72];          // [c][j] fp16 u (18.4 KB)
    __shared__ __align__(16) char scratch[18432];  // E16 / Sx / St (18.4 KB)
    __shared__ float2 wTpow[7][N_];                // 1.8 KB
    unsigned short* E16 = (unsigned short*)scratch;   // [m(64)][c] stride 136
    float2*         Sx  = (float2*)scratch;           // [n(32)][c(64)]
    unsigned short* St  = (unsigned short*)scratch;   // [c(128)][m'] stride 72

    if (tid < N_) {
        int idx = h * N_ + tid;
        float dt = expf(log_dt[h]);
        float Ar = -expf(log_A_real[idx]);
        float Ai = A_imag[idx];
        float ar = dt * Ar * (float)T_, ai = dt * Ai * (float)T_;
        float er = expf(ar);
        float pr = er * cosf(ai), pi = er * sinf(ai);
#pragma unroll
        for (int k = 0; k < 7; ++k) {
            wTpow[k][tid] = make_float2(pr, pi);
            float nr = pr * pr - pi * pi;
            pi = 2.f * pr * pi; pr = nr;
        }
    }

    // ---- stage: u = enc(x) -> Ut[c][j] fp16 ----
    const float ew0 = enc_w[h], ew1 = enc_w[H_ + h], eb = enc_b[h];
    {
        int c = tid >> 1, j0 = (tid & 1) * 32;
        const float4* xp = (const float4*)((const float2*)x + (size_t)b * L_
                                           + c * 64 + j0);
#pragma unroll
        for (int i = 0; i < 16; ++i) {
            float4 xv = xp[i];
            float u0 = fmaf(xv.x, ew0, fmaf(xv.y, ew1, eb));
            float u1 = fmaf(xv.z, ew0, fmaf(xv.w, ew1, eb));
            unsigned int pk = (unsigned)f2h(u0) | ((unsigned)f2h(u1) << 16);
            *(unsigned int*)&Ut[c][j0 + 2 * i] = pk;
        }
    }
    __syncthreads();

    // ---- GEMM E[m 64][c 128] = V[m][j] @ U[j][c] -> fp16 E16 ----
    {
        f32x4 acc[8];
#pragma unroll
        for (int nt = 0; nt < 8; ++nt) acc[nt] = (f32x4){0.f, 0.f, 0.f, 0.f};
        const unsigned short* Arow = Vh + h * 4096 + (wq * 16 + mrow) * 64;
#pragma unroll
        for (int ks = 0; ks < 2; ++ks) {
            int k0 = ks * 32 + quad * 8;
            half8 af = *(const half8*)(Arow + k0);
#pragma unroll
            for (int nt = 0; nt < 8; ++nt) {
                half8 bf = *(const half8*)&Ut[nt * 16 + mrow][k0];
                acc[nt] = __builtin_amdgcn_mfma_f32_16x16x32_f16(
                    af, bf, acc[nt], 0, 0, 0);
            }
        }
#pragma unroll
        for (int nt = 0; nt < 8; ++nt) {
            int cc = nt * 16 + mrow;
#pragma unroll
            for (int r = 0; r < 4; ++r)
                E16[(wq * 16 + quad * 4 + r) * 136 + cc] = f2h(acc[nt][r]);
        }
    }
    __syncthreads();

    // ---- scan: 4 waves, wave = (cHalf, nHalf), 16 n per thread ----
    float zr[16], zi[16];
    const int cHalf = wq & 1, nHalf = wq >> 1;
    const int n0 = nHalf * 16;
    const int c = cHalf * 64 + lane;
#pragma unroll
    for (int j = 0; j < 16; ++j) {
        zr[j] = h2f(E16[(n0 + j) * 136 + c]);
        zi[j] = h2f(E16[(32 + n0 + j) * 136 + c]);
    }
    __syncthreads();            // all E16 reads done before Sx overwrites
#pragma unroll
    for (int k = 0; k < 6; ++k) {
        int s = 1 << k;
        float mask = (lane >= s) ? 1.f : 0.f;
#pragma unroll
        for (int j = 0; j < 16; ++j) {
            float2 q = wTpow[k][n0 + j];
            float vr = __shfl_up(zr[j], s, 64);
            float vi = __shfl_up(zi[j], s, 64);
            float adr = fmaf(q.x, vr, -(q.y * vi));
            float adi = fmaf(q.x, vi, q.y * vr);
            zr[j] = fmaf(mask, adr, zr[j]);
            zi[j] = fmaf(mask, adi, zi[j]);
        }
    }
    if (cHalf == 0) {           // publish inclusive scans of low c-half
#pragma unroll
        for (int j = 0; j < 16; ++j)
            Sx[(n0 + j) * 64 + lane] = make_float2(zr[j], zi[j]);
    }
    __syncthreads();
    if (cHalf == 1) {           // s=64 combine with uniform weight wT^64
#pragma unroll
        for (int j = 0; j < 16; ++j) {
            float2 q = wTpow[6][n0 + j];
            float2 v = Sx[(n0 + j) * 64 + lane];
            zr[j] = fmaf(q.x, v.x, fmaf(-q.y, v.y, zr[j]));
            zi[j] = fmaf(q.x, v.y, fmaf(q.y, v.x, zi[j]));
        }
    }
    {                           // shift by one chunk: S_in[c] = I[c-1]
        bool l0 = (lane == 0);
#pragma unroll
        for (int j = 0; j < 16; ++j) {
            float2 bv = Sx[(n0 + j) * 64 + 63];
            float br = (cHalf == 1) ? bv.x : 0.f;
            float bi = (cHalf == 1) ? bv.y : 0.f;
            float tr = __shfl_up(zr[j], 1, 64);
            float ti = __shfl_up(zi[j], 1, 64);
            zr[j] = l0 ? br : tr;
            zi[j] = l0 ? bi : ti;
        }
    }
    __syncthreads();            // all Sx reads done before St overwrites
    {
#pragma unroll
        for (int j2 = 0; j2 < 8; ++j2) {
            unsigned int p0 = (unsigned)f2h(zr[2 * j2]) |
                              ((unsigned)f2h(zr[2 * j2 + 1]) << 16);
            unsigned int p1 = (unsigned)f2h(zi[2 * j2]) |
                              ((unsigned)f2h(zi[2 * j2 + 1]) << 16);
            *(unsigned int*)&St[c * 72 + n0 + 2 * j2] = p0;
            *(unsigned int*)&St[c * 72 + 32 + n0 + 2 * j2] = p1;
        }
    }
    __syncthreads();

    // ---- GEMM Y[t][c] = Klo@U + P@S; epilogue u from Ut; fp16 gy store ----
    {
        f32x4 acc[8];
#pragma unroll
        for (int nt = 0; nt < 8; ++nt) acc[nt] = (f32x4){0.f, 0.f, 0.f, 0.f};
        const unsigned short* Krow = Kh + h * 4096 + (wq * 16 + mrow) * 64;
#pragma unroll
        for (int ks = 0; ks < 2; ++ks) {
            int k0 = ks * 32 + quad * 8;
            half8 af = *(const half8*)(Krow + k0);
#pragma unroll
            for (int nt = 0; nt < 8; ++nt) {
                half8 bf = *(const half8*)&Ut[nt * 16 + mrow][k0];
                acc[nt] = __builtin_amdgcn_mfma_f32_16x16x32_f16(
                    af, bf, acc[nt], 0, 0, 0);
            }
        }
        const unsigned short* Prow = Ph + h * 4096 + (wq * 16 + mrow) * 64;
#pragma unroll
        for (int ks = 0; ks < 2; ++ks) {
            int k0 = ks * 32 + quad * 8;
            half8 af = *(const half8*)(Prow + k0);
#pragma unroll
            for (int nt = 0; nt < 8; ++nt) {
                half8 bf = *(const half8*)&St[(nt * 16 + mrow) * 72 + k0];
                acc[nt] = __builtin_amdgcn_mfma_f32_16x16x32_f16(
                    af, bf, acc[nt], 0, 0, 0);
            }
        }
        const float Dh = Dp[h];
        unsigned short* gyb = gy + (size_t)bh * L_;
#pragma unroll
        for (int nt = 0; nt < 8; ++nt) {
            int cc = nt * 16 + mrow;
#pragma unroll
            for (int r = 0; r < 4; ++r) {
                int t = wq * 16 + quad * 4 + r;
                float u = h2f(Ut[cc][t]);
                float y = fmaf(Dh, u, acc[nt][r]);
                gyb[t * 128 + cc] = f2h(gelu_tanh(y));
            }
        }
    }
}

// ---------------------------------------------------------------------------
// k_mix: fp16 MFMA GLU mix + pooled decode (R14 version — no fence/atomic).
// ---------------------------------------------------------------------------
#define BPAD 136
__global__ __launch_bounds__(256) void k_mix(
    const unsigned short* __restrict__ Wh, const unsigned short* __restrict__ gy,
    const float* __restrict__ out_b, const float* __restrict__ dec_w,
    float* __restrict__ part)
{
    __shared__ unsigned short Bt[64 * BPAD];   // [v][h] fp16 tile (17.4 KB)
    __shared__ float red[4];

    const int blk = blockIdx.x;                // = b*128 + t*2 + ch
    const int b = blk >> 7;
    const int t = (blk >> 1) & 63, ch = blk & 1;
    const int tid = threadIdx.x;
    const int wq = tid >> 6, lane = tid & 63;

    // ---- stage: 128h x 64v fp16 transpose (uint4 = 8 ushorts per load) ----
    const unsigned short* gsrc = gy + (size_t)(b * H_) * L_ + t * 128 + ch * 64;
#pragma unroll
    for (int it = 0; it < 4; ++it) {
        int idx = it * 256 + tid;
        int h = idx >> 3, v0 = (idx & 7) * 8;
        uint4 q = *(const uint4*)(gsrc + (size_t)h * L_ + v0);
        Bt[(v0 + 0) * BPAD + h] = (unsigned short)(q.x & 0xFFFF);
        Bt[(v0 + 1) * BPAD + h] = (unsigned short)(q.x >> 16);
        Bt[(v0 + 2) * BPAD + h] = (unsigned short)(q.y & 0xFFFF);
        Bt[(v0 + 3) * BPAD + h] = (unsigned short)(q.y >> 16);
        Bt[(v0 + 4) * BPAD + h] = (unsigned short)(q.z & 0xFFFF);
        Bt[(v0 + 5) * BPAD + h] = (unsigned short)(q.z >> 16);
        Bt[(v0 + 6) * BPAD + h] = (unsigned short)(q.w & 0xFFFF);
        Bt[(v0 + 7) * BPAD + h] = (unsigned short)(q.w >> 16);
    }
    __syncthreads();

    const int ga = wq * 32;
    const int gg = 128 + wq * 32;
    const int mrow = lane & 15;
    const int quad = lane >> 4;
    f32x4 accA[2][4], accG[2][4];
#pragma unroll
    for (int mt = 0; mt < 2; ++mt)
#pragma unroll
        for (int nt = 0; nt < 4; ++nt) {
            accA[mt][nt] = (f32x4){0.f, 0.f, 0.f, 0.f};
            accG[mt][nt] = (f32x4){0.f, 0.f, 0.f, 0.f};
        }

#pragma unroll
    for (int k = 0; k < 4; ++k) {
        const int h0 = k * 32 + quad * 8;
        half8 bfr[4];
#pragma unroll
        for (int nt = 0; nt < 4; ++nt) {
            int v = nt * 16 + mrow;
            bfr[nt] = *(const half8*)(Bt + v * BPAD + h0);
        }
#pragma unroll
        for (int mt = 0; mt < 2; ++mt) {
            half8 ah = *(const half8*)(Wh + (ga + mt * 16 + mrow) * 128 + h0);
            half8 ag = *(const half8*)(Wh + (gg + mt * 16 + mrow) * 128 + h0);
#pragma unroll
            for (int nt = 0; nt < 4; ++nt) {
                accA[mt][nt] = __builtin_amdgcn_mfma_f32_16x16x32_f16(
                    ah, bfr[nt], accA[mt][nt], 0, 0, 0);
                accG[mt][nt] = __builtin_amdgcn_mfma_f32_16x16x32_f16(
                    ag, bfr[nt], accG[mt][nt], 0, 0, 0);
            }
        }
    }

    float s = 0.f;
#pragma unroll
    for (int mt = 0; mt < 2; ++mt) {
        float4 obA = *(const float4*)(out_b + ga + mt * 16 + quad * 4);
        float4 obG = *(const float4*)(out_b + gg + mt * 16 + quad * 4);
        float4 dv  = *(const float4*)(dec_w + ga + mt * 16 + quad * 4);
#pragma unroll
        for (int nt = 0; nt < 4; ++nt) {
#pragma unroll
            for (int r = 0; r < 4; ++r) {
                float a  = accA[mt][nt][r] + ((const float*)&obA)[r];
                float zg = accG[mt][nt][r] + ((const float*)&obG)[r];
                float sig = __fdividef(1.f, 1.f + __expf(-zg));
                s = fmaf(((const float*)&dv)[r], a * sig, s);
            }
        }
    }
#pragma unroll
    for (int off = 32; off; off >>= 1) s += __shfl_down(s, off, 64);
    if (lane == 0) red[wq] = s;
    __syncthreads();
    if (tid == 0) part[blk] = red[0] + red[1] + red[2] + red[3];
}

// ---------------------------------------------------------------------------
__global__ __launch_bounds__(512) void k_final(
    const float* __restrict__ part, const float* __restrict__ dec_b,
    float* __restrict__ out)
{
    int tid = threadIdx.x;
    int b = tid >> 6, lane = tid & 63;
    float s = part[b * 128 + lane] + part[b * 128 + 64 + lane];
#pragma unroll
    for (int off = 32; off; off >>= 1) s += __shfl_down(s, off, 64);
    if (lane == 0) out[b] = fmaf(s, 1.0f / (float)L_, dec_b[0]);
}

// ---------------------------------------------------------------------------
extern "C" void kernel_launch(void* const* d_in, const int* in_sizes, int n_in,
                              void* d_out, int out_size, void* d_ws, size_t ws_size,
                              hipStream_t stream)
{
    const float* x         = (const float*)d_in[0];
    const float* enc_w     = (const float*)d_in[1];
    const float* enc_b     = (const float*)d_in[2];
    const float* log_dt    = (const float*)d_in[3];
    const float* log_A_real= (const float*)d_in[4];
    const float* A_imag    = (const float*)d_in[5];
    const float* C_re      = (const float*)d_in[6];
    const float* C_im      = (const float*)d_in[7];
    const float* Dp        = (const float*)d_in[8];
    const float* out_w     = (const float*)d_in[9];
    const float* out_b     = (const float*)d_in[10];
    const float* dec_w     = (const float*)d_in[11];
    const float* dec_b     = (const float*)d_in[12];
    float* out = (float*)d_out;

    char* ws = (char*)d_ws;
    unsigned short* Wh = (unsigned short*)(ws);
    unsigned short* Kh = (unsigned short*)(ws + 65536);
    unsigned short* Ph = (unsigned short*)(ws + 1114112);
    unsigned short* Vh = (unsigned short*)(ws + 2162688);
    unsigned short* gy = (unsigned short*)(ws + 3211264);
    float* part        = (float*)(ws + 19988480);

    k_prep<<<3 * H_, 256, 0, stream>>>(log_dt, log_A_real, A_imag, C_re, C_im,
                                       out_w, Wh, Kh, Ph, Vh);
    k_s4d<<<B_ * H_, 256, 0, stream>>>(x, enc_w, enc_b, log_dt, log_A_real,
                                       A_imag, Dp, Kh, Ph, Vh, gy);
    k_mix<<<B_ * 128, 256, 0, stream>>>(Wh, gy, out_b, dec_w, part);
    k_final<<<1, 512, 0, stream>>>(part, dec_b, out);
}

// Round 17
// 138.824 us; speedup vs baseline: 1.1540x; 1.0140x over previous
//
#include <hip/hip_runtime.h>
#include <math.h>

// Problem dims (fixed by the reference)
#define B_ 8
#define L_ 8192
#define H_ 128
#define N_ 32
#define C_ 128   // chunks along L
#define T_ 64    // chunk length

// ws layout:
//   Wh   ushort[256*128]     @ 0        (64 KB)  fp16 out_w [g][h]
//   Kh   ushort[128*64*64]   @ 65536    (1 MB)   fp16 Klo[h][t][j] (Toeplitz)
//   Ph   ushort[128*64*64]   @ 1114112  (1 MB)   fp16 P[h][t][m']  (state inj)
//   Vh   ushort[128*64*64]   @ 2162688  (1 MB)   fp16 V[h][m'][j]  (Vandermonde)
//   gy   ushort[B_*H_*L_]    @ 3211264  (16 MB)  fp16 gy [b][h][l'], l'=t*128+c
//   part float[1024]         @ 19988480 (4 KB)

typedef _Float16 half8 __attribute__((ext_vector_type(8)));
typedef __attribute__((ext_vector_type(4))) float f32x4;

__device__ __forceinline__ float gelu_tanh(float y) {
    float t = 0.7978845608028654f * fmaf(0.044715f, y * y * y, y);
    float e = __expf(2.f * t);
    float th = 1.f - __fdividef(2.f, e + 1.f);
    return 0.5f * y * (1.f + th);
}
__device__ __forceinline__ unsigned short f2h(float f) {
    _Float16 h = (_Float16)f;
    return *(unsigned short*)&h;
}
__device__ __forceinline__ float h2f(unsigned short u) {
    return (float)(*(const _Float16*)&u);
}

// ---------------------------------------------------------------------------
// k_prep: per-h fp16 matrices Klo/P/V + Wh (out_w fp16). Block = h.
// R14 128-block version (R16's 384-block split measured neutral-to-negative).
// ---------------------------------------------------------------------------
__global__ __launch_bounds__(256) void k_prep(
    const float* __restrict__ log_dt, const float* __restrict__ log_A_real,
    const float* __restrict__ A_imag, const float* __restrict__ C_re,
    const float* __restrict__ C_im, const float* __restrict__ out_w,
    unsigned short* __restrict__ Wh, unsigned short* __restrict__ Kh,
    unsigned short* __restrict__ Ph, unsigned short* __restrict__ Vh)
{
    const int h = blockIdx.x;
    const int tid = threadIdx.x;
    __shared__ float2 wtab[65][N_];
    __shared__ float2 coefs[N_];
    __shared__ float Kd[64];

    float dt = expf(log_dt[h]);
#pragma unroll
    for (int it = 0; it < 9; ++it) {
        int idx = it * 256 + tid;
        if (idx < 65 * N_) {
            int d = idx >> 5, n = idx & 31;
            float Ar = -expf(log_A_real[h * N_ + n]);
            float Ai = A_imag[h * N_ + n];
            float ar = dt * Ar * (float)d, ai = dt * Ai * (float)d;
            float er = expf(ar);
            wtab[d][n] = make_float2(er * cosf(ai), er * sinf(ai));
        }
    }
    if (tid < N_) {
        int n = tid;
        float Ar = -expf(log_A_real[h * N_ + n]);
        float Ai = A_imag[h * N_ + n];
        float ar = dt * Ar, ai = dt * Ai;
        float er = expf(ar);
        float wr = er * cosf(ai), wi = er * sinf(ai);
        float inv = 1.f / (Ar * Ar + Ai * Ai);
        float numr = wr - 1.f, numi = wi;
        float qr = (numr * Ar + numi * Ai) * inv;
        float qi = (numi * Ar - numr * Ai) * inv;
        coefs[n] = make_float2(C_re[h * N_ + n] * qr - C_im[h * N_ + n] * qi,
                               C_re[h * N_ + n] * qi + C_im[h * N_ + n] * qr);
    }
    __syncthreads();
    if (tid < 64) {
        float s = 0.f;
#pragma unroll
        for (int n = 0; n < N_; ++n) {
            float2 cf = coefs[n]; float2 w = wtab[tid][n];
            s += cf.x * w.x - cf.y * w.y;
        }
        Kd[tid] = 2.f * s;
    }
    __syncthreads();
#pragma unroll
    for (int it = 0; it < 16; ++it) {
        int idx = it * 256 + tid;              // t*64 + j
        int t = idx >> 6, j = idx & 63;
        Kh[h * 4096 + idx] = f2h((t >= j) ? Kd[t - j] : 0.f);
    }
#pragma unroll
    for (int it = 0; it < 16; ++it) {
        int idx = it * 256 + tid;              // t*64 + m
        int t = idx >> 6, m = idx & 63, n = m & 31;
        float2 cf = coefs[n]; float2 w = wtab[t + 1][n];
        float re = cf.x * w.x - cf.y * w.y;
        float im = cf.x * w.y + cf.y * w.x;
        Ph[h * 4096 + idx] = f2h((m < 32) ? 2.f * re : -2.f * im);
    }
#pragma unroll
    for (int it = 0; it < 16; ++it) {
        int idx = it * 256 + tid;              // m*64 + j
        int m = idx >> 6, j = idx & 63, n = m & 31;
        float2 w = wtab[63 - j][n];
        Vh[h * 4096 + idx] = f2h((m < 32) ? w.x : w.y);
    }
    {   // out_w rows g = 2h, 2h+1 -> fp16
        int g = 2 * h + (tid >> 7), j = tid & 127;
        Wh[g * 128 + j] = f2h(out_w[g * 128 + j]);
    }
}

// ---------------------------------------------------------------------------
// k_s4d: MFMA-Toeplitz S4D (UNCHANGED from R14).
// ---------------------------------------------------------------------------
__global__ __launch_bounds__(256) void k_s4d(
    const float* __restrict__ x, const float* __restrict__ enc_w,
    const float* __restrict__ enc_b, const float* __restrict__ log_dt,
    const float* __restrict__ log_A_real, const float* __restrict__ A_imag,
    const float* __restrict__ Dp, const unsigned short* __restrict__ Kh,
    const unsigned short* __restrict__ Ph, const unsigned short* __restrict__ Vh,
    unsigned short* __restrict__ gy)
{
    const int bh = blockIdx.x;
    const int b = bh >> 7, h = bh & (H_ - 1);
    const int tid = threadIdx.x;
    const int lane = tid & 63, wq = tid >> 6;
    const int mrow = lane & 15, quad = lane >> 4;

    __shared__ unsigned short Ut[C_][72];          // [c][j] fp16 u (18.4 KB)
    __shared__ __align__(16) char scratch[18432];  // E16 / Sx / St (18.4 KB)
    __shared__ float2 wTpow[7][N_];                // 1.8 KB
    unsigned short* E16 = (unsigned short*)scratch;   // [m(64)][c] stride 136
    float2*         Sx  = (float2*)scratch;           // [n(32)][c(64)]
    unsigned short* St  = (unsigned short*)scratch;   // [c(128)][m'] stride 72

    if (tid < N_) {
        int idx = h * N_ + tid;
        float dt = expf(log_dt[h]);
        float Ar = -expf(log_A_real[idx]);
        float Ai = A_imag[idx];
        float ar = dt * Ar * (float)T_, ai = dt * Ai * (float)T_;
        float er = expf(ar);
        float pr = er * cosf(ai), pi = er * sinf(ai);
#pragma unroll
        for (int k = 0; k < 7; ++k) {
            wTpow[k][tid] = make_float2(pr, pi);
            float nr = pr * pr - pi * pi;
            pi = 2.f * pr * pi; pr = nr;
        }
    }

    // ---- stage: u = enc(x) -> Ut[c][j] fp16 ----
    const float ew0 = enc_w[h], ew1 = enc_w[H_ + h], eb = enc_b[h];
    {
        int c = tid >> 1, j0 = (tid & 1) * 32;
        const float4* xp = (const float4*)((const float2*)x + (size_t)b * L_
                                           + c * 64 + j0);
#pragma unroll
        for (int i = 0; i < 16; ++i) {
            float4 xv = xp[i];
            float u0 = fmaf(xv.x, ew0, fmaf(xv.y, ew1, eb));
            float u1 = fmaf(xv.z, ew0, fmaf(xv.w, ew1, eb));
            unsigned int pk = (unsigned)f2h(u0) | ((unsigned)f2h(u1) << 16);
            *(unsigned int*)&Ut[c][j0 + 2 * i] = pk;
        }
    }
    __syncthreads();

    // ---- GEMM E[m 64][c 128] = V[m][j] @ U[j][c] -> fp16 E16 ----
    {
        f32x4 acc[8];
#pragma unroll
        for (int nt = 0; nt < 8; ++nt) acc[nt] = (f32x4){0.f, 0.f, 0.f, 0.f};
        const unsigned short* Arow = Vh + h * 4096 + (wq * 16 + mrow) * 64;
#pragma unroll
        for (int ks = 0; ks < 2; ++ks) {
            int k0 = ks * 32 + quad * 8;
            half8 af = *(const half8*)(Arow + k0);
#pragma unroll
            for (int nt = 0; nt < 8; ++nt) {
                half8 bf = *(const half8*)&Ut[nt * 16 + mrow][k0];
                acc[nt] = __builtin_amdgcn_mfma_f32_16x16x32_f16(
                    af, bf, acc[nt], 0, 0, 0);
            }
        }
#pragma unroll
        for (int nt = 0; nt < 8; ++nt) {
            int cc = nt * 16 + mrow;
#pragma unroll
            for (int r = 0; r < 4; ++r)
                E16[(wq * 16 + quad * 4 + r) * 136 + cc] = f2h(acc[nt][r]);
        }
    }
    __syncthreads();

    // ---- scan: 4 waves, wave = (cHalf, nHalf), 16 n per thread ----
    float zr[16], zi[16];
    const int cHalf = wq & 1, nHalf = wq >> 1;
    const int n0 = nHalf * 16;
    const int c = cHalf * 64 + lane;
#pragma unroll
    for (int j = 0; j < 16; ++j) {
        zr[j] = h2f(E16[(n0 + j) * 136 + c]);
        zi[j] = h2f(E16[(32 + n0 + j) * 136 + c]);
    }
    __syncthreads();            // all E16 reads done before Sx overwrites
#pragma unroll
    for (int k = 0; k < 6; ++k) {
        int s = 1 << k;
        float mask = (lane >= s) ? 1.f : 0.f;
#pragma unroll
        for (int j = 0; j < 16; ++j) {
            float2 q = wTpow[k][n0 + j];
            float vr = __shfl_up(zr[j], s, 64);
            float vi = __shfl_up(zi[j], s, 64);
            float adr = fmaf(q.x, vr, -(q.y * vi));
            float adi = fmaf(q.x, vi, q.y * vr);
            zr[j] = fmaf(mask, adr, zr[j]);
            zi[j] = fmaf(mask, adi, zi[j]);
        }
    }
    if (cHalf == 0) {           // publish inclusive scans of low c-half
#pragma unroll
        for (int j = 0; j < 16; ++j)
            Sx[(n0 + j) * 64 + lane] = make_float2(zr[j], zi[j]);
    }
    __syncthreads();
    if (cHalf == 1) {           // s=64 combine with uniform weight wT^64
#pragma unroll
        for (int j = 0; j < 16; ++j) {
            float2 q = wTpow[6][n0 + j];
            float2 v = Sx[(n0 + j) * 64 + lane];
            zr[j] = fmaf(q.x, v.x, fmaf(-q.y, v.y, zr[j]));
            zi[j] = fmaf(q.x, v.y, fmaf(q.y, v.x, zi[j]));
        }
    }
    {                           // shift by one chunk: S_in[c] = I[c-1]
        bool l0 = (lane == 0);
#pragma unroll
        for (int j = 0; j < 16; ++j) {
            float2 bv = Sx[(n0 + j) * 64 + 63];
            float br = (cHalf == 1) ? bv.x : 0.f;
            float bi = (cHalf == 1) ? bv.y : 0.f;
            float tr = __shfl_up(zr[j], 1, 64);
            float ti = __shfl_up(zi[j], 1, 64);
            zr[j] = l0 ? br : tr;
            zi[j] = l0 ? bi : ti;
        }
    }
    __syncthreads();            // all Sx reads done before St overwrites
    {
#pragma unroll
        for (int j2 = 0; j2 < 8; ++j2) {
            unsigned int p0 = (unsigned)f2h(zr[2 * j2]) |
                              ((unsigned)f2h(zr[2 * j2 + 1]) << 16);
            unsigned int p1 = (unsigned)f2h(zi[2 * j2]) |
                              ((unsigned)f2h(zi[2 * j2 + 1]) << 16);
            *(unsigned int*)&St[c * 72 + n0 + 2 * j2] = p0;
            *(unsigned int*)&St[c * 72 + 32 + n0 + 2 * j2] = p1;
        }
    }
    __syncthreads();

    // ---- GEMM Y[t][c] = Klo@U + P@S; epilogue u from Ut; fp16 gy store ----
    {
        f32x4 acc[8];
#pragma unroll
        for (int nt = 0; nt < 8; ++nt) acc[nt] = (f32x4){0.f, 0.f, 0.f, 0.f};
        const unsigned short* Krow = Kh + h * 4096 + (wq * 16 + mrow) * 64;
#pragma unroll
        for (int ks = 0; ks < 2; ++ks) {
            int k0 = ks * 32 + quad * 8;
            half8 af = *(const half8*)(Krow + k0);
#pragma unroll
            for (int nt = 0; nt < 8; ++nt) {
                half8 bf = *(const half8*)&Ut[nt * 16 + mrow][k0];
                acc[nt] = __builtin_amdgcn_mfma_f32_16x16x32_f16(
                    af, bf, acc[nt], 0, 0, 0);
            }
        }
        const unsigned short* Prow = Ph + h * 4096 + (wq * 16 + mrow) * 64;
#pragma unroll
        for (int ks = 0; ks < 2; ++ks) {
            int k0 = ks * 32 + quad * 8;
            half8 af = *(const half8*)(Prow + k0);
#pragma unroll
            for (int nt = 0; nt < 8; ++nt) {
                half8 bf = *(const half8*)&St[(nt * 16 + mrow) * 72 + k0];
                acc[nt] = __builtin_amdgcn_mfma_f32_16x16x32_f16(
                    af, bf, acc[nt], 0, 0, 0);
            }
        }
        const float Dh = Dp[h];
        unsigned short* gyb = gy + (size_t)bh * L_;
#pragma unroll
        for (int nt = 0; nt < 8; ++nt) {
            int cc = nt * 16 + mrow;
#pragma unroll
            for (int r = 0; r < 4; ++r) {
                int t = wq * 16 + quad * 4 + r;
                float u = h2f(Ut[cc][t]);
                float y = fmaf(Dh, u, acc[nt][r]);
                gyb[t * 128 + cc] = f2h(gelu_tanh(y));
            }
        }
    }
}

// ---------------------------------------------------------------------------
// k_mix: fp16 MFMA GLU mix + pooled decode (UNCHANGED from R14).
// ---------------------------------------------------------------------------
#define BPAD 136
__global__ __launch_bounds__(256) void k_mix(
    const unsigned short* __restrict__ Wh, const unsigned short* __restrict__ gy,
    const float* __restrict__ out_b, const float* __restrict__ dec_w,
    float* __restrict__ part)
{
    __shared__ unsigned short Bt[64 * BPAD];   // [v][h] fp16 tile (17.4 KB)
    __shared__ float red[4];

    const int blk = blockIdx.x;                // = b*128 + t*2 + ch
    const int b = blk >> 7;
    const int t = (blk >> 1) & 63, ch = blk & 1;
    const int tid = threadIdx.x;
    const int wq = tid >> 6, lane = tid & 63;

    // ---- stage: 128h x 64v fp16 transpose (uint4 = 8 ushorts per load) ----
    const unsigned short* gsrc = gy + (size_t)(b * H_) * L_ + t * 128 + ch * 64;
#pragma unroll
    for (int it = 0; it < 4; ++it) {
        int idx = it * 256 + tid;
        int h = idx >> 3, v0 = (idx & 7) * 8;
        uint4 q = *(const uint4*)(gsrc + (size_t)h * L_ + v0);
        Bt[(v0 + 0) * BPAD + h] = (unsigned short)(q.x & 0xFFFF);
        Bt[(v0 + 1) * BPAD + h] = (unsigned short)(q.x >> 16);
        Bt[(v0 + 2) * BPAD + h] = (unsigned short)(q.y & 0xFFFF);
        Bt[(v0 + 3) * BPAD + h] = (unsigned short)(q.y >> 16);
        Bt[(v0 + 4) * BPAD + h] = (unsigned short)(q.z & 0xFFFF);
        Bt[(v0 + 5) * BPAD + h] = (unsigned short)(q.z >> 16);
        Bt[(v0 + 6) * BPAD + h] = (unsigned short)(q.w & 0xFFFF);
        Bt[(v0 + 7) * BPAD + h] = (unsigned short)(q.w >> 16);
    }
    __syncthreads();

    const int ga = wq * 32;
    const int gg = 128 + wq * 32;
    const int mrow = lane & 15;
    const int quad = lane >> 4;
    f32x4 accA[2][4], accG[2][4];
#pragma unroll
    for (int mt = 0; mt < 2; ++mt)
#pragma unroll
        for (int nt = 0; nt < 4; ++nt) {
            accA[mt][nt] = (f32x4){0.f, 0.f, 0.f, 0.f};
            accG[mt][nt] = (f32x4){0.f, 0.f, 0.f, 0.f};
        }

#pragma unroll
    for (int k = 0; k < 4; ++k) {
        const int h0 = k * 32 + quad * 8;
        half8 bfr[4];
#pragma unroll
        for (int nt = 0; nt < 4; ++nt) {
            int v = nt * 16 + mrow;
            bfr[nt] = *(const half8*)(Bt + v * BPAD + h0);
        }
#pragma unroll
        for (int mt = 0; mt < 2; ++mt) {
            half8 ah = *(const half8*)(Wh + (ga + mt * 16 + mrow) * 128 + h0);
            half8 ag = *(const half8*)(Wh + (gg + mt * 16 + mrow) * 128 + h0);
#pragma unroll
            for (int nt = 0; nt < 4; ++nt) {
                accA[mt][nt] = __builtin_amdgcn_mfma_f32_16x16x32_f16(
                    ah, bfr[nt], accA[mt][nt], 0, 0, 0);
                accG[mt][nt] = __builtin_amdgcn_mfma_f32_16x16x32_f16(
                    ag, bfr[nt], accG[mt][nt], 0, 0, 0);
            }
        }
    }

    float s = 0.f;
#pragma unroll
    for (int mt = 0; mt < 2; ++mt) {
        float4 obA = *(const float4*)(out_b + ga + mt * 16 + quad * 4);
        float4 obG = *(const float4*)(out_b + gg + mt * 16 + quad * 4);
        float4 dv  = *(const float4*)(dec_w + ga + mt * 16 + quad * 4);
#pragma unroll
        for (int nt = 0; nt < 4; ++nt) {
#pragma unroll
            for (int r = 0; r < 4; ++r) {
                float a  = accA[mt][nt][r] + ((const float*)&obA)[r];
                float zg = accG[mt][nt][r] + ((const float*)&obG)[r];
                float sig = __fdividef(1.f, 1.f + __expf(-zg));
                s = fmaf(((const float*)&dv)[r], a * sig, s);
            }
        }
    }
#pragma unroll
    for (int off = 32; off; off >>= 1) s += __shfl_down(s, off, 64);
    if (lane == 0) red[wq] = s;
    __syncthreads();
    if (tid == 0) part[blk] = red[0] + red[1] + red[2] + red[3];
}

// ---------------------------------------------------------------------------
__global__ __launch_bounds__(512) void k_final(
    const float* __restrict__ part, const float* __restrict__ dec_b,
    float* __restrict__ out)
{
    int tid = threadIdx.x;
    int b = tid >> 6, lane = tid & 63;
    float s = part[b * 128 + lane] + part[b * 128 + 64 + lane];
#pragma unroll
    for (int off = 32; off; off >>= 1) s += __shfl_down(s, off, 64);
    if (lane == 0) out[b] = fmaf(s, 1.0f / (float)L_, dec_b[0]);
}

// ---------------------------------------------------------------------------
extern "C" void kernel_launch(void* const* d_in, const int* in_sizes, int n_in,
                              void* d_out, int out_size, void* d_ws, size_t ws_size,
                              hipStream_t stream)
{
    const float* x         = (const float*)d_in[0];
    const float* enc_w     = (const float*)d_in[1];
    const float* enc_b     = (const float*)d_in[2];
    const float* log_dt    = (const float*)d_in[3];
    const float* log_A_real= (const float*)d_in[4];
    const float* A_imag    = (const float*)d_in[5];
    const float* C_re      = (const float*)d_in[6];
    const float* C_im      = (const float*)d_in[7];
    const float* Dp        = (const float*)d_in[8];
    const float* out_w     = (const float*)d_in[9];
    const float* out_b     = (const float*)d_in[10];
    const float* dec_w     = (const float*)d_in[11];
    const float* dec_b     = (const float*)d_in[12];
    float* out = (float*)d_out;

    char* ws = (char*)d_ws;
    unsigned short* Wh = (unsigned short*)(ws);
    unsigned short* Kh = (unsigned short*)(ws + 65536);
    unsigned short* Ph = (unsigned short*)(ws + 1114112);
    unsigned short* Vh = (unsigned short*)(ws + 2162688);
    unsigned short* gy = (unsigned short*)(ws + 3211264);
    float* part        = (float*)(ws + 19988480);

    k_prep<<<H_, 256, 0, stream>>>(log_dt, log_A_real, A_imag, C_re, C_im,
                                   out_w, Wh, Kh, Ph, Vh);
    k_s4d<<<B_ * H_, 256, 0, stream>>>(x, enc_w, enc_b, log_dt, log_A_real,
                                       A_imag, Dp, Kh, Ph, Vh, gy);
    k_mix<<<B_ * 128, 256, 0, stream>>>(Wh, gy, out_b, dec_w, part);
    k_final<<<1, 512, 0, stream>>>(part, dec_b, out);
}